// Round 16
// baseline (53.469 us; speedup 1.0000x reference)
//
#include <hip/hip_runtime.h>

#define DIM 256
#define T_LEN 4096
#define K_CODES 1024
#define N_TOK 65536
#define NELEM 16777216

// ws layout (32-bit units):
//   [0,1024)       cnh2[k] packed (bf16_hi | bf16_lo<<16) of 128 + 128*|e_k|^2
//   [1024,1536)    loss partials (512 f32)
//   [4096,69632)   cbb8: fp8(256*cb), MX-tiled 256 KB (r14 layout)
// Score: s' = 128 + 128|e|^2 - 256*(e_fp8 . x_fp8) in ~[80,180] > 0.

typedef __attribute__((ext_vector_type(8))) short bf16x8;
typedef __attribute__((ext_vector_type(16))) float f32x16;
typedef __attribute__((ext_vector_type(8))) int i32x8;

__device__ __forceinline__ unsigned short f2bf(float f) {
    unsigned u = __builtin_bit_cast(unsigned, f);
    return (unsigned short)((u + 0x7FFFu + ((u >> 16) & 1u)) >> 16);
}
__device__ __forceinline__ float bf2f(unsigned short h) {
    return __builtin_bit_cast(float, (unsigned)h << 16);
}
__device__ __forceinline__ unsigned f2u(float f) { return __builtin_bit_cast(unsigned, f); }
__device__ __forceinline__ float u2f(unsigned u) { return __builtin_bit_cast(float, u); }
__device__ __forceinline__ unsigned umin2(unsigned a, unsigned b) { return a < b ? a : b; }

union FragU { bf16x8 v; unsigned short u[8]; };

#define GLLOAD(gsrc, lbase)                                                              \
    __builtin_amdgcn_global_load_lds(                                                    \
        (const __attribute__((address_space(1))) unsigned int*)(gsrc),                   \
        (__attribute__((address_space(3))) unsigned int*)(lbase), 16, 0, 0)

__device__ __forceinline__ unsigned cvt8n(float a, float b) {
    unsigned r;
    asm("v_cvt_pk_fp8_f32 %0, -%1, -%2" : "=v"(r) : "v"(a), "v"(b));
    return r;
}
__device__ __forceinline__ unsigned cvt8(float a, float b) {
    unsigned r;
    asm("v_cvt_pk_fp8_f32 %0, %1, %2" : "=v"(r) : "v"(a), "v"(b));
    return r;
}

// ---------------- prep: cb -> fp8(256x, MX-tiled) + cnh2 (r14-identical) ----------------
__global__ __launch_bounds__(256) void prep(const float* __restrict__ cb,
                                            char* __restrict__ cbb8,
                                            unsigned* __restrict__ cnh2) {
    const int k = blockIdx.x * 4 + (threadIdx.x >> 6);
    const int lane = threadIdx.x & 63;
    float4 v = *reinterpret_cast<const float4*>(cb + (size_t)k * DIM + lane * 4);
    float s = v.x * v.x + v.y * v.y + v.z * v.z + v.w * v.w;
    #pragma unroll
    for (int off = 32; off; off >>= 1) s += __shfl_down(s, off);
    if (lane == 0) {
        float cn = 128.0f + 128.0f * s;
        unsigned short chi = f2bf(cn);
        unsigned short clo = f2bf(cn - bf2f(chi));
        cnh2[k] = (unsigned)chi | ((unsigned)clo << 16);
    }
    const unsigned wlo = cvt8(256.0f * v.x, 256.0f * v.y);
    const unsigned whi = cvt8(256.0f * v.z, 256.0f * v.w);
    const unsigned dw = __builtin_amdgcn_perm(whi, wlo, 0x05040100u);
    const int d0 = lane * 4;
    const int wnd = d0 >> 6, dwi = d0 & 63, hs = dwi >> 5, i = dwi & 31;
    const int byte = (k >> 5) * 8192 + wnd * 2048 + hs * 1024 + (i >> 4) * 512
                   + (k & 31) * 16 + (i & 15);
    *reinterpret_cast<unsigned*>(cbb8 + byte) = dw;
}

// ---------------- fused pipelined: [ingest A][sweep A + ingest B][sweep B + scatter A][scatter B] ----------------
__global__ __launch_bounds__(256, 2) void vq_fused(const float* __restrict__ x,
                                                   const char* __restrict__ cbb8,
                                                   const unsigned* __restrict__ cnh2,
                                                   const float* __restrict__ cbf,
                                                   float* __restrict__ out,
                                                   float* __restrict__ part) {
    __shared__ __align__(16) char ring[32768];        // staging dbuf / tile-A transpose
    __shared__ __align__(16) char xbuf[16384];        // tile-B transpose / scatter-A tile
    __shared__ unsigned cnl[1024];
    __shared__ unsigned kbx[4][32];
    __shared__ int kklA[64], kklB[64];
    __shared__ float wsum[4];
    const int tid = threadIdx.x;
    const int w = tid >> 6, lane = tid & 63, hi = lane >> 5, ln31 = lane & 31;
    const int tg = w >> 1, kh = w & 1;
    const int tw0 = blockIdx.x * 128;
    const int b = tw0 >> 12, tb = tw0 & (T_LEN - 1);

    cnl[tid] = cnh2[tid];
    cnl[tid + 256] = cnh2[tid + 256];
    cnl[tid + 512] = cnh2[tid + 512];
    cnl[tid + 768] = cnh2[tid + 768];

    const int tqi = tid & 15, cqi = tid >> 4;
    float x2s = 0.0f;

    // ---- ingest helpers (r15-identical math) ----
    auto ing_load = [&](const float* xbase, int ii, float4* P) {
        const int cl = (ii * 16 + cqi) * 4;
        const float* p = xbase + (size_t)cl * T_LEN;
        P[0] = *reinterpret_cast<const float4*>(p);
        P[1] = *reinterpret_cast<const float4*>(p + T_LEN);
        P[2] = *reinterpret_cast<const float4*>(p + 2 * T_LEN);
        P[3] = *reinterpret_cast<const float4*>(p + 3 * T_LEN);
    };
    auto ing_proc = [&](int ii, const float4* P, char* lds) {
        const int cl = (ii * 16 + cqi) * 4;
        x2s = fmaf(P[0].x, P[0].x, fmaf(P[0].y, P[0].y, fmaf(P[0].z, P[0].z, fmaf(P[0].w, P[0].w, x2s))));
        x2s = fmaf(P[1].x, P[1].x, fmaf(P[1].y, P[1].y, fmaf(P[1].z, P[1].z, fmaf(P[1].w, P[1].w, x2s))));
        x2s = fmaf(P[2].x, P[2].x, fmaf(P[2].y, P[2].y, fmaf(P[2].z, P[2].z, fmaf(P[2].w, P[2].w, x2s))));
        x2s = fmaf(P[3].x, P[3].x, fmaf(P[3].y, P[3].y, fmaf(P[3].z, P[3].z, fmaf(P[3].w, P[3].w, x2s))));
        const unsigned lo0 = cvt8n(P[0].x, P[0].y), hi0 = cvt8n(P[0].z, P[0].w);
        const unsigned lo1 = cvt8n(P[1].x, P[1].y), hi1 = cvt8n(P[1].z, P[1].w);
        const unsigned lo2 = cvt8n(P[2].x, P[2].y), hi2 = cvt8n(P[2].z, P[2].w);
        const unsigned lo3 = cvt8n(P[3].x, P[3].y), hi3 = cvt8n(P[3].z, P[3].w);
        const unsigned s01 = __builtin_amdgcn_perm(lo1, lo0, 0x05010400u);
        const unsigned s23 = __builtin_amdgcn_perm(lo3, lo2, 0x05010400u);
        const unsigned u01 = __builtin_amdgcn_perm(hi1, hi0, 0x05010400u);
        const unsigned u23 = __builtin_amdgcn_perm(hi3, hi2, 0x05010400u);
        const unsigned t0 = __builtin_amdgcn_perm(s23, s01, 0x05040100u);
        const unsigned t1 = __builtin_amdgcn_perm(s23, s01, 0x07060302u);
        const unsigned t2 = __builtin_amdgcn_perm(u23, u01, 0x05040100u);
        const unsigned t3 = __builtin_amdgcn_perm(u23, u01, 0x07060302u);
        const int ta = 4 * tqi;
        *reinterpret_cast<unsigned*>(lds + (ta + 0) * 256 + (cl ^ (((ta + 0) & 15) << 3))) = t0;
        *reinterpret_cast<unsigned*>(lds + (ta + 1) * 256 + (cl ^ (((ta + 1) & 15) << 3))) = t1;
        *reinterpret_cast<unsigned*>(lds + (ta + 2) * 256 + (cl ^ (((ta + 2) & 15) << 3))) = t2;
        *reinterpret_cast<unsigned*>(lds + (ta + 3) * 256 + (cl ^ (((ta + 3) & 15) << 3))) = t3;
    };
    auto read_frags = [&](const char* src, i32x8* xf) {
        const int tp0 = tg * 32 + ln31;
        const int z0 = (tp0 & 15) << 3;
        #pragma unroll
        for (int wnd = 0; wnd < 4; ++wnd) {
            #pragma unroll
            for (int g = 0; g < 4; ++g) {
                const int o = wnd * 64 + hi * 32 + g * 8;
                const long v0 = *reinterpret_cast<const long*>(src + tp0 * 256 + (o ^ z0));
                xf[wnd][2 * g] = (int)(unsigned)(v0 & 0xFFFFFFFFu);
                xf[wnd][2 * g + 1] = (int)(unsigned)(((unsigned long)v0) >> 32);
            }
        }
    };
    auto stage = [&](int kc, int buf) {
        char* lb = ring + buf * 16384 + w * 1024;
        const char* gc = cbb8 + kc * 8192;
        #pragma unroll
        for (int j = 0; j < 4; ++j) {
            const int o = j * 4096 + tid * 16;
            GLLOAD(gc + (o & 8191) + (o >> 13) * 131072, lb + j * 4096);
        }
    };

    FragU onef;
    #pragma unroll
    for (int i = 0; i < 8; ++i) onef.u[i] = (hi == 0 && i < 2) ? 0x3F80 : 0;

    auto mfma_round = [&](const i32x8* xf, int cur, int kc, unsigned& ba, unsigned& bb) {
        const unsigned d = cnl[kh * 512 + kc * 32 + ln31];
        FragU cfr0;
        #pragma unroll
        for (int i = 0; i < 8; ++i) cfr0.u[i] = 0;
        if (hi == 0) {
            cfr0.u[0] = (unsigned short)(d & 0xFFFFu);
            cfr0.u[1] = (unsigned short)(d >> 16);
        }
        f32x16 acc0;
        #pragma unroll
        for (int i = 0; i < 16; ++i) acc0[i] = 0.0f;
        acc0 = __builtin_amdgcn_mfma_f32_32x32x16_bf16(cfr0.v, onef.v, acc0, 0, 0, 0);
        const char* cbpA = ring + cur * 16384 + kh * 8192 + hi * 1024 + ln31 * 16;
        #pragma unroll
        for (int wnd = 0; wnd < 4; ++wnd) {
            const uint4 alo = *reinterpret_cast<const uint4*>(cbpA + wnd * 2048);
            const uint4 ahi = *reinterpret_cast<const uint4*>(cbpA + wnd * 2048 + 512);
            i32x8 aw;
            aw[0] = (int)alo.x; aw[1] = (int)alo.y; aw[2] = (int)alo.z; aw[3] = (int)alo.w;
            aw[4] = (int)ahi.x; aw[5] = (int)ahi.y; aw[6] = (int)ahi.z; aw[7] = (int)ahi.w;
            acc0 = __builtin_amdgcn_mfma_scale_f32_32x32x64_f8f6f4(
                aw, xf[wnd], acc0, 0, 0, 0, 0x7F7F7F7F, 0, 0x7F7F7F7F);
        }
        const int kbl = kh * 512 + kc * 32 + hi * 4;
        #pragma unroll
        for (int rg = 0; rg < 16; ++rg) {
            const unsigned kk = (unsigned)(kbl + (rg & 3) + 8 * (rg >> 2));
            const unsigned p0 = (f2u(acc0[rg]) & 0xFFFFFC00u) | kk;
            if (rg & 1) bb = umin2(bb, p0);
            else        ba = umin2(ba, p0);
        }
    };

    const float* xbA = x + (size_t)b * DIM * T_LEN + tb + 4 * tqi;
    const float* xbB = xbA + 64;

    // ---- phase 0: ingest tile A (full) ----
    #pragma unroll
    for (int ii = 0; ii < 4; ++ii) {
        float4 P[4];
        ing_load(xbA, ii, P);
        ing_proc(ii, P, ring);
    }
    __syncthreads();
    i32x8 xfA[4];
    read_frags(ring, xfA);
    __syncthreads();

    stage(0, 0);
    unsigned a0 = 0xFFFFFFFFu, a1 = 0xFFFFFFFFu;

    // ---- sweep A; rounds 0-3 carry tile-B ingest ----
    for (int kc = 0; kc < 16; ++kc) {
        const int cur = kc & 1;
        float4 PB[4];
        const bool ing = (kc < 4);
        if (kc < 15) {
            if (ing) ing_load(xbB, kc, PB);          // issued BEFORE stage -> older
            __builtin_amdgcn_sched_barrier(0);
            stage(kc + 1, cur ^ 1);
            if (ing) asm volatile("s_waitcnt vmcnt(8)" ::: "memory");
            else     asm volatile("s_waitcnt vmcnt(4)" ::: "memory");
        } else {
            asm volatile("s_waitcnt vmcnt(0)" ::: "memory");
        }
        __builtin_amdgcn_s_barrier();
        __builtin_amdgcn_sched_barrier(0);
        mfma_round(xfA, cur, kc, a0, a1);
        __builtin_amdgcn_sched_barrier(0);
        if (ing) ing_proc(kc, PB, xbuf);             // consume: compiler waits vmcnt(4)
        __builtin_amdgcn_s_barrier();
        __builtin_amdgcn_sched_barrier(0);
    }

    // ---- epilogue A (keys only; loss folded into x2s) ----
    unsigned bestA = umin2(a0, a1);
    bestA = umin2(bestA, __shfl_xor(bestA, 32));
    if (hi == 0) kbx[w][ln31] = bestA;
    __syncthreads();
    if (tid < 64) {
        const int tgn = tid >> 5, t32 = tid & 31;
        const unsigned key = umin2(kbx[tgn * 2][t32], kbx[tgn * 2 + 1][t32]);
        kklA[tid] = (int)(key & 1023u);
        x2s += (u2f(key & 0xFFFFFC00u) - 128.0f) * 0.0078125f;
    }
    i32x8 xfB[4];
    read_frags(xbuf, xfB);                           // lgkm drained by next barrier
    __syncthreads();                                 // kklA visible; xbuf reads done
    const int ttS = tid & 63, chS = tid >> 6;
    const size_t rowbA = (size_t)kklA[ttS] * DIM;
    float* fs = (float*)xbuf;

    stage(0, 0);
    unsigned c0 = 0xFFFFFFFFu, c1 = 0xFFFFFFFFu;
    float4 G0 = {0, 0, 0, 0}, G1 = {0, 0, 0, 0};

    // ---- sweep B; carries scatter A (slice s: gather@2s, fs-write@2s+1, out@2s+2) ----
    for (int kc = 0; kc < 16; ++kc) {
        const int cur = kc & 1;
        if (kc < 15) {
            stage(kc + 1, cur ^ 1);
            if (kc == 0)      { asm volatile("s_waitcnt vmcnt(4)" ::: "memory"); }
            else if (kc == 1) { asm volatile("s_waitcnt vmcnt(6)" ::: "memory"); }
            else if (kc & 1)  { asm volatile("s_waitcnt vmcnt(8)" ::: "memory"); }
            else              { asm volatile("s_waitcnt vmcnt(4)" ::: "memory"); }
        } else {
            asm volatile("s_waitcnt vmcnt(0)" ::: "memory");
        }
        __builtin_amdgcn_s_barrier();
        __builtin_amdgcn_sched_barrier(0);
        if (kc & 1) {                                // fs-write slice (kc-1)/2
            const int c0i = chS * 8;
            fs[(c0i + 0) * 68 + ttS] = G0.x;
            fs[(c0i + 1) * 68 + ttS] = G0.y;
            fs[(c0i + 2) * 68 + ttS] = G0.z;
            fs[(c0i + 3) * 68 + ttS] = G0.w;
            fs[(c0i + 4) * 68 + ttS] = G1.x;
            fs[(c0i + 5) * 68 + ttS] = G1.y;
            fs[(c0i + 6) * 68 + ttS] = G1.z;
            fs[(c0i + 7) * 68 + ttS] = G1.w;
        } else if (kc >= 2) {                        // out-write slice (kc-2)/2
            const int sl = (kc - 2) >> 1;
            #pragma unroll
            for (int p = 0; p < 2; ++p) {
                const int c = tid >> 3, tq = (tid & 7) + p * 8;
                const float4 v = *reinterpret_cast<const float4*>(fs + c * 68 + tq * 4);
                *reinterpret_cast<float4*>(
                    out + (((size_t)(b * DIM + sl * 32 + c)) << 12) + tb + tq * 4) = v;
            }
        }
        __builtin_amdgcn_sched_barrier(0);
        mfma_round(xfB, cur, kc, c0, c1);
        __builtin_amdgcn_sched_barrier(0);
        if (!(kc & 1)) {                             // gather slice kc/2
            const int sl = kc >> 1;
            G0 = *reinterpret_cast<const float4*>(cbf + rowbA + sl * 32 + chS * 8);
            G1 = *reinterpret_cast<const float4*>(cbf + rowbA + sl * 32 + chS * 8 + 4);
        }
        __builtin_amdgcn_s_barrier();
        __builtin_amdgcn_sched_barrier(0);
    }

    // slice 7 of scatter A: out-write
    #pragma unroll
    for (int p = 0; p < 2; ++p) {
        const int c = tid >> 3, tq = (tid & 7) + p * 8;
        const float4 v = *reinterpret_cast<const float4*>(fs + c * 68 + tq * 4);
        *reinterpret_cast<float4*>(
            out + (((size_t)(b * DIM + 224 + c)) << 12) + tb + tq * 4) = v;
    }

    // ---- epilogue B ----
    unsigned bestB = umin2(c0, c1);
    bestB = umin2(bestB, __shfl_xor(bestB, 32));
    if (hi == 0) kbx[w][ln31] = bestB;
    __syncthreads();
    if (tid < 64) {
        const int tgn = tid >> 5, t32 = tid & 31;
        const unsigned key = umin2(kbx[tgn * 2][t32], kbx[tgn * 2 + 1][t32]);
        kklB[tid] = (int)(key & 1023u);
        x2s += (u2f(key & 0xFFFFFC00u) - 128.0f) * 0.0078125f;
    }
    __syncthreads();

    // loss partial (both tiles)
    float red = x2s;
    #pragma unroll
    for (int off = 32; off; off >>= 1) red += __shfl_down(red, off);
    if (lane == 0) wsum[w] = red;
    __syncthreads();
    if (tid == 0) part[blockIdx.x] = wsum[0] + wsum[1] + wsum[2] + wsum[3];

    // ---- scatter B (standard 8 slices through fs) ----
    const size_t rowbB = (size_t)kklB[ttS] * DIM;
    #pragma unroll 1
    for (int sl = 0; sl < 8; ++sl) {
        float4 g0 = *reinterpret_cast<const float4*>(cbf + rowbB + sl * 32 + chS * 8);
        float4 g1 = *reinterpret_cast<const float4*>(cbf + rowbB + sl * 32 + chS * 8 + 4);
        __syncthreads();
        const int c0i = chS * 8;
        fs[(c0i + 0) * 68 + ttS] = g0.x;
        fs[(c0i + 1) * 68 + ttS] = g0.y;
        fs[(c0i + 2) * 68 + ttS] = g0.z;
        fs[(c0i + 3) * 68 + ttS] = g0.w;
        fs[(c0i + 4) * 68 + ttS] = g1.x;
        fs[(c0i + 5) * 68 + ttS] = g1.y;
        fs[(c0i + 6) * 68 + ttS] = g1.z;
        fs[(c0i + 7) * 68 + ttS] = g1.w;
        __syncthreads();
        #pragma unroll
        for (int p = 0; p < 2; ++p) {
            const int c = tid >> 3, tq = (tid & 7) + p * 8;
            const float4 v = *reinterpret_cast<const float4*>(fs + c * 68 + tq * 4);
            *reinterpret_cast<float4*>(
                out + (((size_t)(b * DIM + sl * 32 + c)) << 12) + tb + 64 + tq * 4) = v;
        }
    }
}

// ---------------- finalize loss ----------------
__global__ __launch_bounds__(256) void finalize(const float* __restrict__ part,
                                                float* __restrict__ loss_out) {
    double s = (double)part[threadIdx.x] + (double)part[threadIdx.x + 256];
    #pragma unroll
    for (int off = 32; off; off >>= 1) s += __shfl_down(s, off);
    __shared__ double wsum[4];
    const int lane = threadIdx.x & 63, wv = threadIdx.x >> 6;
    if (lane == 0) wsum[wv] = s;
    __syncthreads();
    if (threadIdx.x == 0)
        *loss_out = (float)(2.0 * (wsum[0] + wsum[1] + wsum[2] + wsum[3]) / (double)NELEM);
}

extern "C" void kernel_launch(void* const* d_in, const int* in_sizes, int n_in,
                              void* d_out, int out_size, void* d_ws, size_t ws_size,
                              hipStream_t stream) {
    const float* x  = (const float*)d_in[0];    // [16,256,4096]
    const float* cb = (const float*)d_in[1];    // [1024,256]
    float* out = (float*)d_out;                 // quant (16777216) + loss (1)
    unsigned* ws = (unsigned*)d_ws;
    unsigned* cnh2 = ws;                        // 1024 u32
    float* part = (float*)(ws + 1024);          // 512 f32
    char* cbb8 = (char*)(ws + 4096);            // 256 KB fp8 codebook (MX-tiled)

    prep<<<K_CODES / 4, 256, 0, stream>>>(cb, cbb8, cnh2);
    vq_fused<<<N_TOK / 128, 256, 0, stream>>>(x, cbb8, cnh2, cb, out, part);
    finalize<<<1, 256, 0, stream>>>(part, out + NELEM);
}